// Round 7
// baseline (397.504 us; speedup 1.0000x reference)
//
#include <hip/hip_runtime.h>
#include <stdint.h>

typedef unsigned short u16;

#define TN    84768      // B*T*N = 8*12*883
#define NNODE 883
#define DD    128
#define EE    7000
#define FFDIM 2048

typedef short bf16x8 __attribute__((ext_vector_type(8)));
typedef float f32x4  __attribute__((ext_vector_type(4)));
typedef __attribute__((address_space(3))) u16 lds_u16;
typedef const __attribute__((address_space(1))) u16 glb_u16;

__device__ __forceinline__ float bf2f(u16 u) {
    unsigned int x = ((unsigned int)u) << 16;
    return __uint_as_float(x);
}
__device__ __forceinline__ u16 f2bf(float f) {
    unsigned int x = __float_as_uint(f);
    x += 0x7FFFu + ((x >> 16) & 1u);   // round-to-nearest-even
    return (u16)(x >> 16);
}
// sanitize: any Inf/NaN bit pattern -> 0
__device__ __forceinline__ u16 cleanu(u16 u) {
    return (((u >> 7) & 0xFF) == 0xFF) ? (u16)0 : u;
}
__device__ __forceinline__ u16 cleanf(float f) {
    unsigned b = __float_as_uint(f);
    if (((b >> 23) & 0xFF) == 0xFF) return 0;
    return cleanu(f2bf(f));
}
// unpack 8 packed bf16 (uint4) -> 8 floats (even ch in low half)
__device__ __forceinline__ void unpk8(uint4 v, float* o) {
    o[0] = __uint_as_float(v.x << 16); o[1] = __uint_as_float(v.x & 0xFFFF0000u);
    o[2] = __uint_as_float(v.y << 16); o[3] = __uint_as_float(v.y & 0xFFFF0000u);
    o[4] = __uint_as_float(v.z << 16); o[5] = __uint_as_float(v.z & 0xFFFF0000u);
    o[6] = __uint_as_float(v.w << 16); o[7] = __uint_as_float(v.w & 0xFFFF0000u);
}

// -------- dtype detect: bf16-packed vs fp32 --------
__global__ __launch_bounds__(256) void k_detect(const unsigned* __restrict__ x,
                                                int* __restrict__ flag) {
    __shared__ int cnt;
    if (threadIdx.x == 0) cnt = 0;
    __syncthreads();
    unsigned w = x[threadIdx.x];
    unsigned e = (w >> 7) & 0xFF;
    int ok = (e >= 96 && e <= 144) || ((w & 0xFFFFu) == 0);
    atomicAdd(&cnt, ok);
    __syncthreads();
    if (threadIdx.x == 0) flag[0] = (cnt < 200) ? 1 : 0;   // 1 = fp32
}

// -------- fused prep: all weight transposes + param sanitize --------
__global__ __launch_bounds__(256) void k_prep(const void* Wl, const void* Wr,
                                              const void* W1, const void* W2,
                                              const void* bl, const void* br,
                                              const void* att, const void* bgat,
                                              const void* b1, const void* b2,
                                              const void* g1, const void* be1,
                                              const void* g2, const void* be2,
                                              u16* __restrict__ wlrT,
                                              u16* __restrict__ w1T,
                                              u16* __restrict__ w2T,
                                              u16* __restrict__ canon,
                                              const int* __restrict__ flag) {
    int f32 = *flag;
    int i = blockIdx.x * 256 + threadIdx.x;
    if (i < 16384) {
        int r = i >> 7, c = i & 127;
        u16 v = f32 ? cleanf(((const float*)Wl)[i]) : cleanu(((const u16*)Wl)[i]);
        wlrT[c * 128 + r] = v;
    } else if (i < 32768) {
        int idx = i - 16384;
        int r = idx >> 7, c = idx & 127;
        u16 v = f32 ? cleanf(((const float*)Wr)[idx]) : cleanu(((const u16*)Wr)[idx]);
        wlrT[16384 + c * 128 + r] = v;
    } else if (i < 294912) {
        int idx = i - 32768;
        int r = idx >> 11, c = idx & 2047;    // [128][2048]
        u16 v = f32 ? cleanf(((const float*)W1)[idx]) : cleanu(((const u16*)W1)[idx]);
        w1T[c * 128 + r] = v;
    } else if (i < 557056) {
        int idx = i - 294912;
        int r = idx >> 7, c = idx & 127;      // [2048][128]
        u16 v = f32 ? cleanf(((const float*)W2)[idx]) : cleanu(((const u16*)W2)[idx]);
        w2T[c * 2048 + r] = v;
    } else if (i < 560256) {
        int p = i - 557056;
        const void* src; int off;
        if      (p < 128)  { src = bl;   off = 0; }
        else if (p < 256)  { src = br;   off = 128; }
        else if (p < 384)  { src = att;  off = 256; }
        else if (p < 512)  { src = bgat; off = 384; }
        else if (p < 2560) { src = b1;   off = 512; }
        else if (p < 2688) { src = b2;   off = 2560; }
        else if (p < 2816) { src = g1;   off = 2688; }
        else if (p < 2944) { src = be1;  off = 2816; }
        else if (p < 3072) { src = g2;   off = 2944; }
        else               { src = be2;  off = 3072; }
        int j = p - off;
        canon[p] = f32 ? cleanf(((const float*)src)[j]) : cleanu(((const u16*)src)[j]);
    }
}

// -------- CSR of the shared 7000-edge graph (dst-indexed); int32/int64 auto --------
// v2: serial 883-iteration prefix scan replaced by parallel Hillis-Steele
// scan over 1024 LDS slots (10 steps); rest unchanged.
__global__ __launch_bounds__(1024) void k_csr(const int* __restrict__ ew,
                                              int* __restrict__ row_off,
                                              int* __restrict__ col) {
    __shared__ int cnt[NNODE];
    __shared__ int offs[NNODE + 1];
    __shared__ int cur[NNODE];
    __shared__ int sc[1024];
    __shared__ int flag;
    int tid = threadIdx.x;
    if (tid == 0) flag = 0;
    for (int i = tid; i < NNODE; i += 1024) cnt[i] = 0;
    __syncthreads();
    int f = 0;
    for (int j = tid; j < EE; j += 1024) f |= ew[2 * j + 1];
    if (f) atomicOr(&flag, 1);
    __syncthreads();
    bool is32 = (flag != 0);
    for (int e = tid; e < EE; e += 1024) {
        int dst = is32 ? ew[EE + e] : ew[2 * EE + 2 * e];
        if ((unsigned)dst < NNODE) atomicAdd(&cnt[dst], 1);
    }
    __syncthreads();
    // parallel inclusive scan of cnt (padded to 1024 with zeros)
    sc[tid] = (tid < NNODE) ? cnt[tid] : 0;
    __syncthreads();
    for (int off = 1; off < 1024; off <<= 1) {
        int add = (tid >= off) ? sc[tid - off] : 0;
        __syncthreads();
        sc[tid] += add;
        __syncthreads();
    }
    if (tid < NNODE) offs[tid] = (tid == 0) ? 0 : sc[tid - 1];
    if (tid == 0) offs[NNODE] = sc[NNODE - 1];
    __syncthreads();
    for (int i = tid; i < NNODE; i += 1024) cur[i] = offs[i];
    __syncthreads();
    for (int e = tid; e < EE; e += 1024) {
        int src = is32 ? ew[e] : ew[2 * e];
        int dst = is32 ? ew[EE + e] : ew[2 * EE + 2 * e];
        if ((unsigned)dst < NNODE && (unsigned)src < NNODE) {
            int p = atomicAdd(&cur[dst], 1);
            if (p < EE) col[p] = src;
        }
    }
    __syncthreads();
    for (int i = tid; i <= NNODE; i += 1024) row_off[i] = offs[i];
}

// -------- x_l / x_r: [TN,128] @ [128,256] via MFMA --------
__global__ __launch_bounds__(256) void k_linlr(const void* __restrict__ xraw,
                                               const u16* __restrict__ wlrT,  // [256][128]
                                               const u16* __restrict__ canon,
                                               u16* __restrict__ xl, u16* __restrict__ xr,
                                               const int* __restrict__ flag) {
    __shared__ __align__(16) u16 a_tile[64 * 136];
    int f32 = *flag;
    int tid = threadIdx.x;
    int m0 = blockIdx.x * 64;
    for (int it = 0; it < 4; ++it) {
        int idx = it * 256 + tid;
        int row = idx >> 4, cc = idx & 15;
        int gm = m0 + row;
        u16 tmp[8];
#pragma unroll
        for (int j = 0; j < 8; ++j) tmp[j] = 0;
        if (gm < TN) {
            size_t base = (size_t)gm * DD + cc * 8;
            if (f32) {
                float4 v0 = *(const float4*)((const float*)xraw + base);
                float4 v1 = *(const float4*)((const float*)xraw + base + 4);
                tmp[0] = cleanf(v0.x); tmp[1] = cleanf(v0.y);
                tmp[2] = cleanf(v0.z); tmp[3] = cleanf(v0.w);
                tmp[4] = cleanf(v1.x); tmp[5] = cleanf(v1.y);
                tmp[6] = cleanf(v1.z); tmp[7] = cleanf(v1.w);
            } else {
                uint4 v = *(const uint4*)((const u16*)xraw + base);
                unsigned wv[4] = {v.x, v.y, v.z, v.w};
#pragma unroll
                for (int j = 0; j < 8; ++j)
                    tmp[j] = cleanu((u16)((wv[j >> 1] >> ((j & 1) * 16)) & 0xFFFFu));
            }
        }
        uint4 o;
        o.x = (unsigned)tmp[0] | ((unsigned)tmp[1] << 16);
        o.y = (unsigned)tmp[2] | ((unsigned)tmp[3] << 16);
        o.z = (unsigned)tmp[4] | ((unsigned)tmp[5] << 16);
        o.w = (unsigned)tmp[6] | ((unsigned)tmp[7] << 16);
        *(uint4*)(a_tile + row * 136 + cc * 8) = o;
    }
    __syncthreads();
    int wave = tid >> 6, lane = tid & 63, n16 = lane & 15, q = lane >> 4;
    f32x4 acc[16];
#pragma unroll
    for (int t = 0; t < 16; ++t) acc[t] = (f32x4){0, 0, 0, 0};
    const u16* arow = a_tile + (16 * wave + n16) * 136;
#pragma unroll
    for (int ks = 0; ks < 4; ++ks) {
        bf16x8 a = *(const bf16x8*)(arow + ks * 32 + q * 8);
#pragma unroll
        for (int t = 0; t < 16; ++t) {
            bf16x8 b = *(const bf16x8*)(wlrT + ((size_t)(t * 16 + n16)) * DD + ks * 32 + q * 8);
            acc[t] = __builtin_amdgcn_mfma_f32_16x16x32_bf16(a, b, acc[t], 0, 0, 0);
        }
    }
#pragma unroll
    for (int t = 0; t < 16; ++t) {
        int cc = (t & 7) * 16 + n16;
        float bias = bf2f(canon[(t < 8 ? 0 : 128) + cc]);
        u16* dst = (t < 8 ? xl : xr);
#pragma unroll
        for (int reg = 0; reg < 4; ++reg) {
            int mrow = m0 + 16 * wave + 4 * q + reg;
            if (mrow < TN) dst[(size_t)mrow * DD + cc] = f2bf(acc[t][reg] + bias);
        }
    }
}

// -------- 16-lane segment sum --------
__device__ __forceinline__ float segsum16(float p) {
    p += __shfl_xor(p, 1, 16);
    p += __shfl_xor(p, 2, 16);
    p += __shfl_xor(p, 4, 16);
    p += __shfl_xor(p, 8, 16);
    return p;
}

// -------- GATv2 v3: edge-parallel groups --------
// 1 wave/node-instance. grp=lane>>3 processes one of 8 items per batch
// (item 0 = self loop, items 1..deg = CSR edges); sub=lane&7 owns head sub's
// 16 channels. Per-head score is lane-local (NO cross-lane shuffles per edge
// -- the old 3-shfl+exp serial chain per edge is gone). One 3-level xor
// reduce across groups at the end; epilogue (residual+LN1) on lanes 0-7.
// h1 aliases xr: wave reads only its own xr row, writes only its own h1 row.
__global__ __launch_bounds__(256) void k_gat(const void* __restrict__ xraw,
                                             const u16* __restrict__ xl,
                                             const u16* xr,
                                             const u16* __restrict__ canon,
                                             const int* __restrict__ row_off,
                                             const int* __restrict__ col,
                                             u16* h1,
                                             const int* __restrict__ flag) {
    int f32 = *flag;
    int tid = threadIdx.x;
    int wave = tid >> 6, lane = tid & 63;
    int g = blockIdx.x * 4 + wave;             // TN % 4 == 0
    int bt = g / NNODE;
    int i = g - bt * NNODE;
    size_t gbase = (size_t)g * DD;
    const u16* xl_inst = xl + (size_t)bt * NNODE * DD;
    int grp = lane >> 3;        // edge slot within batch
    int cbase = (lane & 7) * 16;   // head (lane&7), channels [cbase, cbase+16)

    // att + xr segments, unpacked once
    float at[16], xrv[16];
    {
        uint4 a0 = *(const uint4*)(canon + 256 + cbase);
        uint4 a1 = *(const uint4*)(canon + 256 + cbase + 8);
        unpk8(a0, at); unpk8(a1, at + 8);
        uint4 r0v = *(const uint4*)(xr + gbase + cbase);
        uint4 r1v = *(const uint4*)(xr + gbase + cbase + 8);
        unpk8(r0v, xrv); unpk8(r1v, xrv + 8);
    }
    float acc[16];
#pragma unroll
    for (int k = 0; k < 16; ++k) acc[k] = 0.f;
    float denom = 0.f;

    int r0 = row_off[i], r1 = row_off[i + 1];
    int nit = (r1 - r0) + 1;                   // self + edges
    for (int base = 0; base < nit; base += 8) {
        int item = base + grp;
        bool valid = item < nit;
        int j;
        if (item == 0) {
            j = i;
        } else {
            int eidx = valid ? (r0 + item - 1) : r0;
            j = col[eidx];
        }
        bool okj = valid && ((unsigned)j < NNODE);
        int jc = okj ? j : 0;
        const u16* rowp = xl_inst + (size_t)jc * DD + cbase;
        uint4 v0 = *(const uint4*)(rowp);
        uint4 v1 = *(const uint4*)(rowp + 8);
        float xv[16];
        unpk8(v0, xv); unpk8(v1, xv + 8);
        float p = 0.f;
#pragma unroll
        for (int k = 0; k < 16; ++k) {
            float u = xv[k] + xrv[k];
            u = fmaxf(u, 0.2f * u);
            p = fmaf(u, at[k], p);
        }
        p = fminf(fmaxf(p, -30.f), 30.f);
        float w = okj ? __expf(p) : 0.f;
        denom += w;
#pragma unroll
        for (int k = 0; k < 16; ++k) acc[k] = fmaf(w, xv[k], acc[k]);
    }
    // reduce across the 8 edge-groups (lanes differing in bits 3..5)
    denom += __shfl_xor(denom, 8);
    denom += __shfl_xor(denom, 16);
    denom += __shfl_xor(denom, 32);
#pragma unroll
    for (int k = 0; k < 16; ++k) {
        acc[k] += __shfl_xor(acc[k], 8);
        acc[k] += __shfl_xor(acc[k], 16);
        acc[k] += __shfl_xor(acc[k], 32);
    }
    if (grp == 0) {            // lanes 0-7: one head each, 16 channels
        float inv = 1.f / denom;
        float bg[16];
        {
            uint4 b0 = *(const uint4*)(canon + 384 + cbase);
            uint4 b1 = *(const uint4*)(canon + 384 + cbase + 8);
            unpk8(b0, bg); unpk8(b1, bg + 8);
        }
        float res[16];
        if (f32) {
            const float* xp = (const float*)xraw + gbase + cbase;
            float4 q0 = *(const float4*)(xp);
            float4 q1 = *(const float4*)(xp + 4);
            float4 q2 = *(const float4*)(xp + 8);
            float4 q3 = *(const float4*)(xp + 12);
            float rr[16] = {q0.x,q0.y,q0.z,q0.w, q1.x,q1.y,q1.z,q1.w,
                            q2.x,q2.y,q2.z,q2.w, q3.x,q3.y,q3.z,q3.w};
#pragma unroll
            for (int k = 0; k < 16; ++k) {
                unsigned b = __float_as_uint(rr[k]);
                res[k] = (((b >> 23) & 0xFF) == 0xFF) ? 0.f : rr[k];
            }
        } else {
            const u16* xp = (const u16*)xraw + gbase + cbase;
            uint4 x0 = *(const uint4*)(xp);
            uint4 x1 = *(const uint4*)(xp + 8);
            unsigned wv[8] = {x0.x,x0.y,x0.z,x0.w, x1.x,x1.y,x1.z,x1.w};
#pragma unroll
            for (int m = 0; m < 8; ++m) {
                res[2*m]   = bf2f(cleanu((u16)(wv[m] & 0xFFFFu)));
                res[2*m+1] = bf2f(cleanu((u16)(wv[m] >> 16)));
            }
        }
        float pre[16];
        float s1 = 0.f, s2 = 0.f;
#pragma unroll
        for (int k = 0; k < 16; ++k) {
            pre[k] = acc[k] * inv + bg[k] + res[k];
            s1 += pre[k]; s2 += pre[k] * pre[k];
        }
        s1 += __shfl_xor(s1, 1, 8); s2 += __shfl_xor(s2, 1, 8);
        s1 += __shfl_xor(s1, 2, 8); s2 += __shfl_xor(s2, 2, 8);
        s1 += __shfl_xor(s1, 4, 8); s2 += __shfl_xor(s2, 4, 8);
        float mu = s1 * (1.0f / 128.0f);
        float var = fmaxf(s2 * (1.0f / 128.0f) - mu * mu, 0.f);
        float rs = rsqrtf(var + 1e-5f);
        float gv[16], bv[16];
        {
            uint4 g0 = *(const uint4*)(canon + 2688 + cbase);
            uint4 g1v = *(const uint4*)(canon + 2688 + cbase + 8);
            unpk8(g0, gv); unpk8(g1v, gv + 8);
            uint4 e0 = *(const uint4*)(canon + 2816 + cbase);
            uint4 e1 = *(const uint4*)(canon + 2816 + cbase + 8);
            unpk8(e0, bv); unpk8(e1, bv + 8);
        }
        unsigned outw[8];
#pragma unroll
        for (int m = 0; m < 8; ++m) {
            float h0 = (pre[2*m]   - mu) * rs * gv[2*m]   + bv[2*m];
            float h1v = (pre[2*m+1] - mu) * rs * gv[2*m+1] + bv[2*m+1];
            outw[m] = (unsigned)f2bf(h0) | ((unsigned)f2bf(h1v) << 16);
        }
        *(uint4*)(h1 + gbase + cbase)     = make_uint4(outw[0], outw[1], outw[2], outw[3]);
        *(uint4*)(h1 + gbase + cbase + 8) = make_uint4(outw[4], outw[5], outw[6], outw[7]);
    }
}

// -------- fused FFN + residual + LN2: M=128/block, wave=32 rows --------
// Round-0 PROVEN version (128.5us). Async DMA weight staging (swizzled);
// every w1b/w2b b-fragment feeds 2 MFMAs (sub-tiles).
// LDS = 16384 + 16384 + 18432 = 51200 B -> 3 blocks/CU.
__global__ __launch_bounds__(256, 3) void k_ffn(const u16* __restrict__ h1,
                                                const u16* __restrict__ w1T,  // [2048][128]
                                                const u16* __restrict__ w2T,  // [128][2048]
                                                const u16* __restrict__ canon,
                                                void* __restrict__ outraw,
                                                const int* __restrict__ flag) {
    __shared__ __align__(16) u16 w1b[64 * 128];   // chunk of W1, swizzled
    __shared__ __align__(16) u16 w2b[128 * 64];   // chunk of W2, swizzled
    __shared__ __align__(16) u16 s_t[128 * 72];   // s = relu(h@W1+b1), padded
    int f32 = *flag;
    int tid = threadIdx.x;
    int wave = tid >> 6, lane = tid & 63, n16 = lane & 15, q = lane >> 4;
    int m0 = blockIdx.x * 128;
    int swz = n16 & 7;
    // A-fragments of h for this wave's 32 rows (2 sub-tiles), regs all kernel
    bf16x8 af[2][4];
#pragma unroll
    for (int sub = 0; sub < 2; ++sub) {
        int gm = m0 + 32 * wave + 16 * sub + n16;
#pragma unroll
        for (int ks = 0; ks < 4; ++ks) {
            if (gm < TN) {
                uint4 v = *(const uint4*)(h1 + (size_t)gm * DD + ks * 32 + q * 8);
                af[sub][ks] = *(const bf16x8*)&v;
            } else {
                uint4 z = make_uint4(0, 0, 0, 0);
                af[sub][ks] = *(const bf16x8*)&z;
            }
        }
    }
    f32x4 acc2[2][8];
#pragma unroll
    for (int sub = 0; sub < 2; ++sub)
#pragma unroll
        for (int t = 0; t < 8; ++t) acc2[sub][t] = (f32x4){0, 0, 0, 0};
    // DMA staging geometry (whole chunk per block)
    int w1r[4], w1b_log[4];
#pragma unroll
    for (int i = 0; i < 4; ++i) {
        w1r[i] = 16 * wave + 4 * i + (lane >> 4);
        w1b_log[i] = (lane & 15) ^ (w1r[i] & 7);
    }
    int w2r[4], w2b_log[4];
#pragma unroll
    for (int i = 0; i < 4; ++i) {
        w2r[i] = 32 * wave + 8 * i + (lane >> 3);
        w2b_log[i] = (lane & 7) ^ (w2r[i] & 7);
    }
    u16* srow_w0 = s_t + (32 * wave + 4 * q) * 72;        // sub0 write rows
    u16* srow_w1 = s_t + (32 * wave + 16 + 4 * q) * 72;   // sub1 write rows
    const u16* srow_r0 = s_t + (32 * wave + n16) * 72;
    const u16* srow_r1 = s_t + (32 * wave + 16 + n16) * 72;
    for (int ch = 0; ch < 32; ++ch) {
        int f0 = ch * 64;
        __syncthreads();   // prior chunk's consumers done
#pragma unroll
        for (int i = 0; i < 4; ++i) {
            glb_u16* g1 = (glb_u16*)(w1T + (size_t)(f0 + w1r[i]) * DD + w1b_log[i] * 8);
            lds_u16* l1 = (lds_u16*)(w1b + (16 * wave + 4 * i) * 128);
            __builtin_amdgcn_global_load_lds((const __attribute__((address_space(1))) unsigned*)g1,
                                             (__attribute__((address_space(3))) unsigned*)l1,
                                             16, 0, 0);
        }
#pragma unroll
        for (int i = 0; i < 4; ++i) {
            glb_u16* g2 = (glb_u16*)(w2T + (size_t)w2r[i] * FFDIM + f0 + w2b_log[i] * 8);
            lds_u16* l2 = (lds_u16*)(w2b + (32 * wave + 8 * i) * 64);
            __builtin_amdgcn_global_load_lds((const __attribute__((address_space(1))) unsigned*)g2,
                                             (__attribute__((address_space(3))) unsigned*)l2,
                                             16, 0, 0);
        }
        __syncthreads();   // drain: staged chunk visible
        // GEMM1: s = relu(h @ W1chunk + b1); each b-frag feeds both sub-tiles
#pragma unroll
        for (int t = 0; t < 4; ++t) {
            f32x4 a10 = (f32x4){0, 0, 0, 0};
            f32x4 a11 = (f32x4){0, 0, 0, 0};
#pragma unroll
            for (int ks = 0; ks < 4; ++ks) {
                bf16x8 b = *(const bf16x8*)(w1b + (t * 16 + n16) * 128 + (((ks * 4 + q) ^ swz) * 8));
                a10 = __builtin_amdgcn_mfma_f32_16x16x32_bf16(af[0][ks], b, a10, 0, 0, 0);
                a11 = __builtin_amdgcn_mfma_f32_16x16x32_bf16(af[1][ks], b, a11, 0, 0, 0);
            }
            float bb = bf2f(canon[512 + f0 + t * 16 + n16]);
#pragma unroll
            for (int reg = 0; reg < 4; ++reg) {
                float v0 = a10[reg] + bb;
                float v1 = a11[reg] + bb;
                v0 = v0 > 0.f ? v0 : 0.f;
                v1 = v1 > 0.f ? v1 : 0.f;
                srow_w0[reg * 72 + t * 16 + n16] = f2bf(v0);
                srow_w1[reg * 72 + t * 16 + n16] = f2bf(v1);
            }
        }
        asm volatile("" ::: "memory");
        // GEMM2: acc2 += s @ W2chunk (s rows wave-private; per-wave DS order ok)
#pragma unroll
        for (int ks2 = 0; ks2 < 2; ++ks2) {
            bf16x8 a20 = *(const bf16x8*)(srow_r0 + ks2 * 32 + q * 8);
            bf16x8 a21 = *(const bf16x8*)(srow_r1 + ks2 * 32 + q * 8);
#pragma unroll
            for (int t = 0; t < 8; ++t) {
                bf16x8 b = *(const bf16x8*)(w2b + (t * 16 + n16) * 64 + (((ks2 * 4 + q) ^ swz) * 8));
                acc2[0][t] = __builtin_amdgcn_mfma_f32_16x16x32_bf16(a20, b, acc2[0][t], 0, 0, 0);
                acc2[1][t] = __builtin_amdgcn_mfma_f32_16x16x32_bf16(a21, b, acc2[1][t], 0, 0, 0);
            }
        }
        asm volatile("" ::: "memory");
    }
    // epilogue: +b2 +residual, LN2 via 16-lane shuffles (row lives in one quad)
    float b2v[8], g2v[8], e2v[8];
#pragma unroll
    for (int t = 0; t < 8; ++t) {
        int col = t * 16 + n16;
        b2v[t] = bf2f(canon[2560 + col]);
        g2v[t] = bf2f(canon[2944 + col]);
        e2v[t] = bf2f(canon[3072 + col]);
    }
#pragma unroll
    for (int sub = 0; sub < 2; ++sub) {
#pragma unroll
        for (int reg = 0; reg < 4; ++reg) {
            int row = 32 * wave + 16 * sub + 4 * q + reg;
            int gm = m0 + row;
            bool ok = gm < TN;
            size_t gb = (size_t)(ok ? gm : 0) * DD;
            float v[8]; float s1 = 0.f, s2 = 0.f;
#pragma unroll
            for (int t = 0; t < 8; ++t) {
                float hres = bf2f(h1[gb + t * 16 + n16]);
                v[t] = acc2[sub][t][reg] + b2v[t] + hres;
                s1 += v[t]; s2 += v[t] * v[t];
            }
            s1 = segsum16(s1);
            s2 = segsum16(s2);
            float mu = s1 * (1.f / 128.f);
            float var = fmaxf(s2 * (1.f / 128.f) - mu * mu, 0.f);
            float rs = rsqrtf(var + 1e-5f);
            if (ok) {
#pragma unroll
                for (int t = 0; t < 8; ++t) {
                    float r = (v[t] - mu) * rs * g2v[t] + e2v[t];
                    if (f32) ((float*)outraw)[gb + t * 16 + n16] = r;
                    else     ((u16*)outraw)[gb + t * 16 + n16] = f2bf(r);
                }
            }
        }
    }
}

extern "C" void kernel_launch(void* const* d_in, const int* in_sizes, int n_in,
                              void* d_out, int out_size, void* d_ws, size_t ws_size,
                              hipStream_t stream) {
    const void* x    = d_in[0];
    const int* eidx  = (const int*)d_in[1];
    const void* Wl   = d_in[2];
    const void* bl   = d_in[3];
    const void* Wr   = d_in[4];
    const void* br   = d_in[5];
    const void* att  = d_in[6];
    const void* bgat = d_in[7];
    const void* W1   = d_in[8];
    const void* b1   = d_in[9];
    const void* W2   = d_in[10];
    const void* b2   = d_in[11];
    const void* g1   = d_in[12];
    const void* be1  = d_in[13];
    const void* g2   = d_in[14];
    const void* be2  = d_in[15];

    // ws layout (bytes): flag@0, rowoff@4096, colw@8192, canon@36864,
    // wlrT@65536, w1T@131072, w2T@655360, xl@1179648, xr/h1@22880256
    char* ws = (char*)d_ws;
    int* flag   = (int*)(ws);
    int* rowoff = (int*)(ws + 4096);
    int* colw   = (int*)(ws + 8192);
    u16* canon  = (u16*)(ws + 36864);
    u16* wlrT   = (u16*)(ws + 65536);
    u16* w1T    = (u16*)(ws + 131072);
    u16* w2T    = (u16*)(ws + 655360);
    u16* xl     = (u16*)(ws + 1179648);
    u16* xr     = (u16*)(ws + 22880256);
    u16* h1     = xr;   // k_gat reads xr[addr] before writing h1[addr]

    k_csr<<<1, 1024, 0, stream>>>(eidx, rowoff, colw);
    k_detect<<<1, 256, 0, stream>>>((const unsigned*)x, flag);
    k_prep<<<2189, 256, 0, stream>>>(Wl, Wr, W1, W2, bl, br, att, bgat, b1, b2,
                                     g1, be1, g2, be2, wlrT, w1T, w2T, canon, flag);
    k_linlr<<<(TN + 63) / 64, 256, 0, stream>>>(x, wlrT, canon, xl, xr, flag);
    k_gat<<<TN / 4, 256, 0, stream>>>(x, xl, xr, canon, rowoff, colw, h1, flag);
    k_ffn<<<(TN + 127) / 128, 256, 0, stream>>>(h1, w1T, w2T, canon, d_out, flag);
}

// Round 8
// 363.545 us; speedup vs baseline: 1.0934x; 1.0934x over previous
//
#include <hip/hip_runtime.h>
#include <stdint.h>

typedef unsigned short u16;

#define TN    84768      // B*T*N = 8*12*883
#define NNODE 883
#define DD    128
#define EE    7000
#define FFDIM 2048

typedef short bf16x8 __attribute__((ext_vector_type(8)));
typedef float f32x4  __attribute__((ext_vector_type(4)));
typedef __attribute__((address_space(3))) u16 lds_u16;
typedef const __attribute__((address_space(1))) u16 glb_u16;

__device__ __forceinline__ float bf2f(u16 u) {
    unsigned int x = ((unsigned int)u) << 16;
    return __uint_as_float(x);
}
__device__ __forceinline__ u16 f2bf(float f) {
    unsigned int x = __float_as_uint(f);
    x += 0x7FFFu + ((x >> 16) & 1u);   // round-to-nearest-even
    return (u16)(x >> 16);
}
// sanitize: any Inf/NaN bit pattern -> 0
__device__ __forceinline__ u16 cleanu(u16 u) {
    return (((u >> 7) & 0xFF) == 0xFF) ? (u16)0 : u;
}
__device__ __forceinline__ u16 cleanf(float f) {
    unsigned b = __float_as_uint(f);
    if (((b >> 23) & 0xFF) == 0xFF) return 0;
    return cleanu(f2bf(f));
}

// -------- dtype detect: bf16-packed vs fp32 --------
__global__ __launch_bounds__(256) void k_detect(const unsigned* __restrict__ x,
                                                int* __restrict__ flag) {
    __shared__ int cnt;
    if (threadIdx.x == 0) cnt = 0;
    __syncthreads();
    unsigned w = x[threadIdx.x];
    unsigned e = (w >> 7) & 0xFF;
    int ok = (e >= 96 && e <= 144) || ((w & 0xFFFFu) == 0);
    atomicAdd(&cnt, ok);
    __syncthreads();
    if (threadIdx.x == 0) flag[0] = (cnt < 200) ? 1 : 0;   // 1 = fp32
}

// -------- fused prep: all weight transposes + param sanitize --------
__global__ __launch_bounds__(256) void k_prep(const void* Wl, const void* Wr,
                                              const void* W1, const void* W2,
                                              const void* bl, const void* br,
                                              const void* att, const void* bgat,
                                              const void* b1, const void* b2,
                                              const void* g1, const void* be1,
                                              const void* g2, const void* be2,
                                              u16* __restrict__ wlrT,
                                              u16* __restrict__ w1T,
                                              u16* __restrict__ w2T,
                                              u16* __restrict__ canon,
                                              const int* __restrict__ flag) {
    int f32 = *flag;
    int i = blockIdx.x * 256 + threadIdx.x;
    if (i < 16384) {
        int r = i >> 7, c = i & 127;
        u16 v = f32 ? cleanf(((const float*)Wl)[i]) : cleanu(((const u16*)Wl)[i]);
        wlrT[c * 128 + r] = v;
    } else if (i < 32768) {
        int idx = i - 16384;
        int r = idx >> 7, c = idx & 127;
        u16 v = f32 ? cleanf(((const float*)Wr)[idx]) : cleanu(((const u16*)Wr)[idx]);
        wlrT[16384 + c * 128 + r] = v;
    } else if (i < 294912) {
        int idx = i - 32768;
        int r = idx >> 11, c = idx & 2047;    // [128][2048]
        u16 v = f32 ? cleanf(((const float*)W1)[idx]) : cleanu(((const u16*)W1)[idx]);
        w1T[c * 128 + r] = v;
    } else if (i < 557056) {
        int idx = i - 294912;
        int r = idx >> 7, c = idx & 127;      // [2048][128]
        u16 v = f32 ? cleanf(((const float*)W2)[idx]) : cleanu(((const u16*)W2)[idx]);
        w2T[c * 2048 + r] = v;
    } else if (i < 560256) {
        int p = i - 557056;
        const void* src; int off;
        if      (p < 128)  { src = bl;   off = 0; }
        else if (p < 256)  { src = br;   off = 128; }
        else if (p < 384)  { src = att;  off = 256; }
        else if (p < 512)  { src = bgat; off = 384; }
        else if (p < 2560) { src = b1;   off = 512; }
        else if (p < 2688) { src = b2;   off = 2560; }
        else if (p < 2816) { src = g1;   off = 2688; }
        else if (p < 2944) { src = be1;  off = 2816; }
        else if (p < 3072) { src = g2;   off = 2944; }
        else               { src = be2;  off = 3072; }
        int j = p - off;
        canon[p] = f32 ? cleanf(((const float*)src)[j]) : cleanu(((const u16*)src)[j]);
    }
}

// -------- CSR of the shared 7000-edge graph (dst-indexed); int32/int64 auto --------
// v2: serial 883-iteration prefix scan replaced by parallel Hillis-Steele
// scan over 1024 LDS slots (10 steps); rest unchanged. (Proven round 7.)
__global__ __launch_bounds__(1024) void k_csr(const int* __restrict__ ew,
                                              int* __restrict__ row_off,
                                              int* __restrict__ col) {
    __shared__ int cnt[NNODE];
    __shared__ int offs[NNODE + 1];
    __shared__ int cur[NNODE];
    __shared__ int sc[1024];
    __shared__ int flag;
    int tid = threadIdx.x;
    if (tid == 0) flag = 0;
    for (int i = tid; i < NNODE; i += 1024) cnt[i] = 0;
    __syncthreads();
    int f = 0;
    for (int j = tid; j < EE; j += 1024) f |= ew[2 * j + 1];
    if (f) atomicOr(&flag, 1);
    __syncthreads();
    bool is32 = (flag != 0);
    for (int e = tid; e < EE; e += 1024) {
        int dst = is32 ? ew[EE + e] : ew[2 * EE + 2 * e];
        if ((unsigned)dst < NNODE) atomicAdd(&cnt[dst], 1);
    }
    __syncthreads();
    // parallel inclusive scan of cnt (padded to 1024 with zeros)
    sc[tid] = (tid < NNODE) ? cnt[tid] : 0;
    __syncthreads();
    for (int off = 1; off < 1024; off <<= 1) {
        int add = (tid >= off) ? sc[tid - off] : 0;
        __syncthreads();
        sc[tid] += add;
        __syncthreads();
    }
    if (tid < NNODE) offs[tid] = (tid == 0) ? 0 : sc[tid - 1];
    if (tid == 0) offs[NNODE] = sc[NNODE - 1];
    __syncthreads();
    for (int i = tid; i < NNODE; i += 1024) cur[i] = offs[i];
    __syncthreads();
    for (int e = tid; e < EE; e += 1024) {
        int src = is32 ? ew[e] : ew[2 * e];
        int dst = is32 ? ew[EE + e] : ew[2 * EE + 2 * e];
        if ((unsigned)dst < NNODE && (unsigned)src < NNODE) {
            int p = atomicAdd(&cur[dst], 1);
            if (p < EE) col[p] = src;
        }
    }
    __syncthreads();
    for (int i = tid; i <= NNODE; i += 1024) row_off[i] = offs[i];
}

// -------- x_l / x_r: [TN,128] @ [128,256] via MFMA --------
__global__ __launch_bounds__(256) void k_linlr(const void* __restrict__ xraw,
                                               const u16* __restrict__ wlrT,  // [256][128]
                                               const u16* __restrict__ canon,
                                               u16* __restrict__ xl, u16* __restrict__ xr,
                                               const int* __restrict__ flag) {
    __shared__ __align__(16) u16 a_tile[64 * 136];
    int f32 = *flag;
    int tid = threadIdx.x;
    int m0 = blockIdx.x * 64;
    for (int it = 0; it < 4; ++it) {
        int idx = it * 256 + tid;
        int row = idx >> 4, cc = idx & 15;
        int gm = m0 + row;
        u16 tmp[8];
#pragma unroll
        for (int j = 0; j < 8; ++j) tmp[j] = 0;
        if (gm < TN) {
            size_t base = (size_t)gm * DD + cc * 8;
            if (f32) {
                float4 v0 = *(const float4*)((const float*)xraw + base);
                float4 v1 = *(const float4*)((const float*)xraw + base + 4);
                tmp[0] = cleanf(v0.x); tmp[1] = cleanf(v0.y);
                tmp[2] = cleanf(v0.z); tmp[3] = cleanf(v0.w);
                tmp[4] = cleanf(v1.x); tmp[5] = cleanf(v1.y);
                tmp[6] = cleanf(v1.z); tmp[7] = cleanf(v1.w);
            } else {
                uint4 v = *(const uint4*)((const u16*)xraw + base);
                unsigned wv[4] = {v.x, v.y, v.z, v.w};
#pragma unroll
                for (int j = 0; j < 8; ++j)
                    tmp[j] = cleanu((u16)((wv[j >> 1] >> ((j & 1) * 16)) & 0xFFFFu));
            }
        }
        uint4 o;
        o.x = (unsigned)tmp[0] | ((unsigned)tmp[1] << 16);
        o.y = (unsigned)tmp[2] | ((unsigned)tmp[3] << 16);
        o.z = (unsigned)tmp[4] | ((unsigned)tmp[5] << 16);
        o.w = (unsigned)tmp[6] | ((unsigned)tmp[7] << 16);
        *(uint4*)(a_tile + row * 136 + cc * 8) = o;
    }
    __syncthreads();
    int wave = tid >> 6, lane = tid & 63, n16 = lane & 15, q = lane >> 4;
    f32x4 acc[16];
#pragma unroll
    for (int t = 0; t < 16; ++t) acc[t] = (f32x4){0, 0, 0, 0};
    const u16* arow = a_tile + (16 * wave + n16) * 136;
#pragma unroll
    for (int ks = 0; ks < 4; ++ks) {
        bf16x8 a = *(const bf16x8*)(arow + ks * 32 + q * 8);
#pragma unroll
        for (int t = 0; t < 16; ++t) {
            bf16x8 b = *(const bf16x8*)(wlrT + ((size_t)(t * 16 + n16)) * DD + ks * 32 + q * 8);
            acc[t] = __builtin_amdgcn_mfma_f32_16x16x32_bf16(a, b, acc[t], 0, 0, 0);
        }
    }
#pragma unroll
    for (int t = 0; t < 16; ++t) {
        int cc = (t & 7) * 16 + n16;
        float bias = bf2f(canon[(t < 8 ? 0 : 128) + cc]);
        u16* dst = (t < 8 ? xl : xr);
#pragma unroll
        for (int reg = 0; reg < 4; ++reg) {
            int mrow = m0 + 16 * wave + 4 * q + reg;
            if (mrow < TN) dst[(size_t)mrow * DD + cc] = f2bf(acc[t][reg] + bias);
        }
    }
}

// -------- 16-lane segment sum --------
__device__ __forceinline__ float segsum16(float p) {
    p += __shfl_xor(p, 1, 16);
    p += __shfl_xor(p, 2, 16);
    p += __shfl_xor(p, 4, 16);
    p += __shfl_xor(p, 8, 16);
    return p;
}

// -------- GATv2: 1 wave/node, 2 packed channels/lane, no-max softmax --------
// v2 (PROVEN rounds 3/6): col[] register-cached (1 load/lane + shfl
// broadcast), xl-row loads software-pipelined 2 deep (A/B rotation).
// NOTE (r7 post-mortem): edge-parallel v3 regressed ~+30us -- VGPR pressure
// + 45% tail-lane waste + lost load pipelining. At deg~9, wave-per-node
// serial edges + TLP wins. Do not revisit without per-kernel counters.
__global__ __launch_bounds__(256) void k_gat(const void* __restrict__ xraw,
                                             const u16* __restrict__ xl,
                                             const u16* xr,
                                             const u16* __restrict__ canon,
                                             const int* __restrict__ row_off,
                                             const int* __restrict__ col,
                                             u16* h1,
                                             const int* __restrict__ flag) {
    int f32 = *flag;
    int tid = threadIdx.x;
    int wave = tid >> 6, lane = tid & 63;
    int g = blockIdx.x * 4 + wave;             // TN % 4 == 0
    int bt = g / NNODE;
    int i = g - bt * NNODE;
    size_t gbase = (size_t)g * DD;
    const u16* xlrow0 = xl + (size_t)bt * NNODE * DD;
    int c2 = lane * 2;
    unsigned uxr = *(const unsigned*)(xr + gbase + c2);
    float xr0 = __uint_as_float(uxr << 16);
    float xr1 = __uint_as_float(uxr & 0xFFFF0000u);
    unsigned uat = *(const unsigned*)(canon + 256 + c2);
    float at0 = __uint_as_float(uat << 16);
    float at1 = __uint_as_float(uat & 0xFFFF0000u);
    unsigned uxs = *(const unsigned*)(xl + gbase + c2);
    float xs0 = __uint_as_float(uxs << 16);
    float xs1 = __uint_as_float(uxs & 0xFFFF0000u);
    float t0 = xs0 + xr0, t1 = xs1 + xr1;
    t0 = fmaxf(t0, 0.2f * t0); t1 = fmaxf(t1, 0.2f * t1);
    float p = t0 * at0 + t1 * at1;
    p += __shfl_xor(p, 1, 8);
    p += __shfl_xor(p, 2, 8);
    p += __shfl_xor(p, 4, 8);
    p = fminf(fmaxf(p, -30.f), 30.f);
    float w = __expf(p);
    float denom = w;
    float a0 = w * xs0, a1 = w * xs1;
    int r0 = row_off[i], r1 = row_off[i + 1];
    int deg = r1 - r0;
    int myj = (lane < deg) ? col[r0 + lane] : 0;   // deg<=64 fast path cache

    // j is wave-uniform (same edge for all lanes) -> branches are uniform
#define NEXTJ(kk) __builtin_amdgcn_readfirstlane(((kk) < 64) ? __shfl(myj, (kk)) : col[r0 + (kk)])
#define EDGE(uvar, okv) do {                                             \
        float _x0 = __uint_as_float((uvar) << 16);                       \
        float _x1 = __uint_as_float((uvar) & 0xFFFF0000u);               \
        float _u0 = _x0 + xr0, _u1 = _x1 + xr1;                          \
        _u0 = fmaxf(_u0, 0.2f * _u0); _u1 = fmaxf(_u1, 0.2f * _u1);      \
        float _q = _u0 * at0 + _u1 * at1;                                \
        _q += __shfl_xor(_q, 1, 8);                                      \
        _q += __shfl_xor(_q, 2, 8);                                      \
        _q += __shfl_xor(_q, 4, 8);                                      \
        _q = fminf(fmaxf(_q, -30.f), 30.f);                              \
        float _w = (okv) ? __expf(_q) : 0.f;                             \
        denom += _w; a0 += _w * _x0; a1 += _w * _x1;                     \
    } while (0)

    unsigned uA = 0, uB = 0;
    bool okA = false, okB = false;
    if (deg > 0) {
        int j = NEXTJ(0); okA = ((unsigned)j < NNODE);
        uA = *(const unsigned*)(xlrow0 + (size_t)(okA ? j : 0) * DD + c2);
    }
    if (deg > 1) {
        int j = NEXTJ(1); okB = ((unsigned)j < NNODE);
        uB = *(const unsigned*)(xlrow0 + (size_t)(okB ? j : 0) * DD + c2);
    }
    int k = 0;
    while (k + 1 < deg) {
        unsigned u = uA; bool ok = okA;
        if (k + 2 < deg) {
            int j = NEXTJ(k + 2); okA = ((unsigned)j < NNODE);
            uA = *(const unsigned*)(xlrow0 + (size_t)(okA ? j : 0) * DD + c2);
        }
        EDGE(u, ok);
        u = uB; ok = okB;
        if (k + 3 < deg) {
            int j = NEXTJ(k + 3); okB = ((unsigned)j < NNODE);
            uB = *(const unsigned*)(xlrow0 + (size_t)(okB ? j : 0) * DD + c2);
        }
        EDGE(u, ok);
        k += 2;
    }
    if (k < deg) EDGE(uA, okA);
#undef EDGE
#undef NEXTJ

    float inv = 1.f / denom;
    unsigned ubg = *(const unsigned*)(canon + 384 + c2);
    float res0, res1;
    if (f32) {
        float2 rr = *(const float2*)((const float*)xraw + gbase + c2);
        unsigned b0 = __float_as_uint(rr.x), b1 = __float_as_uint(rr.y);
        res0 = (((b0 >> 23) & 0xFF) == 0xFF) ? 0.f : rr.x;
        res1 = (((b1 >> 23) & 0xFF) == 0xFF) ? 0.f : rr.y;
    } else {
        unsigned ux = *(const unsigned*)((const u16*)xraw + gbase + c2);
        res0 = bf2f(cleanu((u16)(ux & 0xFFFFu)));
        res1 = bf2f(cleanu((u16)(ux >> 16)));
    }
    float pre0 = a0 * inv + __uint_as_float(ubg << 16) + res0;
    float pre1 = a1 * inv + __uint_as_float(ubg & 0xFFFF0000u) + res1;
    float sum = pre0 + pre1, sq = pre0 * pre0 + pre1 * pre1;
    for (int off = 32; off; off >>= 1) {
        sum += __shfl_xor(sum, off);
        sq  += __shfl_xor(sq, off);
    }
    float mu = sum * (1.0f / 128.0f);
    float var = fmaxf(sq * (1.0f / 128.0f) - mu * mu, 0.f);
    float rs = rsqrtf(var + 1e-5f);
    unsigned ug = *(const unsigned*)(canon + 2688 + c2);
    unsigned ub = *(const unsigned*)(canon + 2816 + c2);
    float h0 = (pre0 - mu) * rs * __uint_as_float(ug << 16) + __uint_as_float(ub << 16);
    float h1v = (pre1 - mu) * rs * __uint_as_float(ug & 0xFFFF0000u) + __uint_as_float(ub & 0xFFFF0000u);
    unsigned out = (unsigned)f2bf(h0) | ((unsigned)f2bf(h1v) << 16);
    *(unsigned*)(h1 + gbase + c2) = out;
}

// -------- fused FFN + residual + LN2: M=128/block, wave=32 rows --------
// Round-0 PROVEN version (128.5us). Async DMA weight staging (swizzled);
// every w1b/w2b b-fragment feeds 2 MFMAs (sub-tiles).
// LDS = 16384 + 16384 + 18432 = 51200 B -> 3 blocks/CU.
__global__ __launch_bounds__(256, 3) void k_ffn(const u16* __restrict__ h1,
                                                const u16* __restrict__ w1T,  // [2048][128]
                                                const u16* __restrict__ w2T,  // [128][2048]
                                                const u16* __restrict__ canon,
                                                void* __restrict__ outraw,
                                                const int* __restrict__ flag) {
    __shared__ __align__(16) u16 w1b[64 * 128];   // chunk of W1, swizzled
    __shared__ __align__(16) u16 w2b[128 * 64];   // chunk of W2, swizzled
    __shared__ __align__(16) u16 s_t[128 * 72];   // s = relu(h@W1+b1), padded
    int f32 = *flag;
    int tid = threadIdx.x;
    int wave = tid >> 6, lane = tid & 63, n16 = lane & 15, q = lane >> 4;
    int m0 = blockIdx.x * 128;
    int swz = n16 & 7;
    // A-fragments of h for this wave's 32 rows (2 sub-tiles), regs all kernel
    bf16x8 af[2][4];
#pragma unroll
    for (int sub = 0; sub < 2; ++sub) {
        int gm = m0 + 32 * wave + 16 * sub + n16;
#pragma unroll
        for (int ks = 0; ks < 4; ++ks) {
            if (gm < TN) {
                uint4 v = *(const uint4*)(h1 + (size_t)gm * DD + ks * 32 + q * 8);
                af[sub][ks] = *(const bf16x8*)&v;
            } else {
                uint4 z = make_uint4(0, 0, 0, 0);
                af[sub][ks] = *(const bf16x8*)&z;
            }
        }
    }
    f32x4 acc2[2][8];
#pragma unroll
    for (int sub = 0; sub < 2; ++sub)
#pragma unroll
        for (int t = 0; t < 8; ++t) acc2[sub][t] = (f32x4){0, 0, 0, 0};
    // DMA staging geometry (whole chunk per block)
    int w1r[4], w1b_log[4];
#pragma unroll
    for (int i = 0; i < 4; ++i) {
        w1r[i] = 16 * wave + 4 * i + (lane >> 4);
        w1b_log[i] = (lane & 15) ^ (w1r[i] & 7);
    }
    int w2r[4], w2b_log[4];
#pragma unroll
    for (int i = 0; i < 4; ++i) {
        w2r[i] = 32 * wave + 8 * i + (lane >> 3);
        w2b_log[i] = (lane & 7) ^ (w2r[i] & 7);
    }
    u16* srow_w0 = s_t + (32 * wave + 4 * q) * 72;        // sub0 write rows
    u16* srow_w1 = s_t + (32 * wave + 16 + 4 * q) * 72;   // sub1 write rows
    const u16* srow_r0 = s_t + (32 * wave + n16) * 72;
    const u16* srow_r1 = s_t + (32 * wave + 16 + n16) * 72;
    for (int ch = 0; ch < 32; ++ch) {
        int f0 = ch * 64;
        __syncthreads();   // prior chunk's consumers done
#pragma unroll
        for (int i = 0; i < 4; ++i) {
            glb_u16* g1 = (glb_u16*)(w1T + (size_t)(f0 + w1r[i]) * DD + w1b_log[i] * 8);
            lds_u16* l1 = (lds_u16*)(w1b + (16 * wave + 4 * i) * 128);
            __builtin_amdgcn_global_load_lds((const __attribute__((address_space(1))) unsigned*)g1,
                                             (__attribute__((address_space(3))) unsigned*)l1,
                                             16, 0, 0);
        }
#pragma unroll
        for (int i = 0; i < 4; ++i) {
            glb_u16* g2 = (glb_u16*)(w2T + (size_t)w2r[i] * FFDIM + f0 + w2b_log[i] * 8);
            lds_u16* l2 = (lds_u16*)(w2b + (32 * wave + 8 * i) * 64);
            __builtin_amdgcn_global_load_lds((const __attribute__((address_space(1))) unsigned*)g2,
                                             (__attribute__((address_space(3))) unsigned*)l2,
                                             16, 0, 0);
        }
        __syncthreads();   // drain: staged chunk visible
        // GEMM1: s = relu(h @ W1chunk + b1); each b-frag feeds both sub-tiles
#pragma unroll
        for (int t = 0; t < 4; ++t) {
            f32x4 a10 = (f32x4){0, 0, 0, 0};
            f32x4 a11 = (f32x4){0, 0, 0, 0};
#pragma unroll
            for (int ks = 0; ks < 4; ++ks) {
                bf16x8 b = *(const bf16x8*)(w1b + (t * 16 + n16) * 128 + (((ks * 4 + q) ^ swz) * 8));
                a10 = __builtin_amdgcn_mfma_f32_16x16x32_bf16(af[0][ks], b, a10, 0, 0, 0);
                a11 = __builtin_amdgcn_mfma_f32_16x16x32_bf16(af[1][ks], b, a11, 0, 0, 0);
            }
            float bb = bf2f(canon[512 + f0 + t * 16 + n16]);
#pragma unroll
            for (int reg = 0; reg < 4; ++reg) {
                float v0 = a10[reg] + bb;
                float v1 = a11[reg] + bb;
                v0 = v0 > 0.f ? v0 : 0.f;
                v1 = v1 > 0.f ? v1 : 0.f;
                srow_w0[reg * 72 + t * 16 + n16] = f2bf(v0);
                srow_w1[reg * 72 + t * 16 + n16] = f2bf(v1);
            }
        }
        asm volatile("" ::: "memory");
        // GEMM2: acc2 += s @ W2chunk (s rows wave-private; per-wave DS order ok)
#pragma unroll
        for (int ks2 = 0; ks2 < 2; ++ks2) {
            bf16x8 a20 = *(const bf16x8*)(srow_r0 + ks2 * 32 + q * 8);
            bf16x8 a21 = *(const bf16x8*)(srow_r1 + ks2 * 32 + q * 8);
#pragma unroll
            for (int t = 0; t < 8; ++t) {
                bf16x8 b = *(const bf16x8*)(w2b + (t * 16 + n16) * 64 + (((ks2 * 4 + q) ^ swz) * 8));
                acc2[0][t] = __builtin_amdgcn_mfma_f32_16x16x32_bf16(a20, b, acc2[0][t], 0, 0, 0);
                acc2[1][t] = __builtin_amdgcn_mfma_f32_16x16x32_bf16(a21, b, acc2[1][t], 0, 0, 0);
            }
        }
        asm volatile("" ::: "memory");
    }
    // epilogue: +b2 +residual, LN2 via 16-lane shuffles (row lives in one quad)
    float b2v[8], g2v[8], e2v[8];
#pragma unroll
    for (int t = 0; t < 8; ++t) {
        int col = t * 16 + n16;
        b2v[t] = bf2f(canon[2560 + col]);
        g2v[t] = bf2f(canon[2944 + col]);
        e2v[t] = bf2f(canon[3072 + col]);
    }
#pragma unroll
    for (int sub = 0; sub < 2; ++sub) {
#pragma unroll
        for (int reg = 0; reg < 4; ++reg) {
            int row = 32 * wave + 16 * sub + 4 * q + reg;
            int gm = m0 + row;
            bool ok = gm < TN;
            size_t gb = (size_t)(ok ? gm : 0) * DD;
            float v[8]; float s1 = 0.f, s2 = 0.f;
#pragma unroll
            for (int t = 0; t < 8; ++t) {
                float hres = bf2f(h1[gb + t * 16 + n16]);
                v[t] = acc2[sub][t][reg] + b2v[t] + hres;
                s1 += v[t]; s2 += v[t] * v[t];
            }
            s1 = segsum16(s1);
            s2 = segsum16(s2);
            float mu = s1 * (1.f / 128.f);
            float var = fmaxf(s2 * (1.f / 128.f) - mu * mu, 0.f);
            float rs = rsqrtf(var + 1e-5f);
            if (ok) {
#pragma unroll
                for (int t = 0; t < 8; ++t) {
                    float r = (v[t] - mu) * rs * g2v[t] + e2v[t];
                    if (f32) ((float*)outraw)[gb + t * 16 + n16] = r;
                    else     ((u16*)outraw)[gb + t * 16 + n16] = f2bf(r);
                }
            }
        }
    }
}

extern "C" void kernel_launch(void* const* d_in, const int* in_sizes, int n_in,
                              void* d_out, int out_size, void* d_ws, size_t ws_size,
                              hipStream_t stream) {
    const void* x    = d_in[0];
    const int* eidx  = (const int*)d_in[1];
    const void* Wl   = d_in[2];
    const void* bl   = d_in[3];
    const void* Wr   = d_in[4];
    const void* br   = d_in[5];
    const void* att  = d_in[6];
    const void* bgat = d_in[7];
    const void* W1   = d_in[8];
    const void* b1   = d_in[9];
    const void* W2   = d_in[10];
    const void* b2   = d_in[11];
    const void* g1   = d_in[12];
    const void* be1  = d_in[13];
    const void* g2   = d_in[14];
    const void* be2  = d_in[15];

    // ws layout (bytes): flag@0, rowoff@4096, colw@8192, canon@36864,
    // wlrT@65536, w1T@131072, w2T@655360, xl@1179648, xr/h1@22880256
    char* ws = (char*)d_ws;
    int* flag   = (int*)(ws);
    int* rowoff = (int*)(ws + 4096);
    int* colw   = (int*)(ws + 8192);
    u16* canon  = (u16*)(ws + 36864);
    u16* wlrT   = (u16*)(ws + 65536);
    u16* w1T    = (u16*)(ws + 131072);
    u16* w2T    = (u16*)(ws + 655360);
    u16* xl     = (u16*)(ws + 1179648);
    u16* xr     = (u16*)(ws + 22880256);
    u16* h1     = xr;   // k_gat reads xr[addr] before writing h1[addr]

    k_csr<<<1, 1024, 0, stream>>>(eidx, rowoff, colw);
    k_detect<<<1, 256, 0, stream>>>((const unsigned*)x, flag);
    k_prep<<<2189, 256, 0, stream>>>(Wl, Wr, W1, W2, bl, br, att, bgat, b1, b2,
                                     g1, be1, g2, be2, wlrT, w1T, w2T, canon, flag);
    k_linlr<<<(TN + 63) / 64, 256, 0, stream>>>(x, wlrT, canon, xl, xr, flag);
    k_gat<<<TN / 4, 256, 0, stream>>>(x, xl, xr, canon, rowoff, colw, h1, flag);
    k_ffn<<<(TN + 127) / 128, 256, 0, stream>>>(h1, w1T, w2T, canon, d_out, flag);
}